// Round 4
// baseline (151.174 us; speedup 1.0000x reference)
//
#include <hip/hip_runtime.h>

typedef __attribute__((ext_vector_type(8)))  __bf16 bvec8;
typedef __attribute__((ext_vector_type(4)))  float  fvec4;
typedef __attribute__((ext_vector_type(16))) float  fvec16;
typedef __attribute__((ext_vector_type(8)))  short  svec8;

__device__ __forceinline__ void gload16(const void* g, void* l) {
    __builtin_amdgcn_global_load_lds(
        (const __attribute__((address_space(1))) void*)g,
        (__attribute__((address_space(3))) void*)l,
        16, 0, 0);
}

__device__ __forceinline__ bvec8 bzero8() {
    svec8 z = (svec8)0;
    return __builtin_bit_cast(bvec8, z);
}

// ---- pack W[l][j][k][i] fp32 -> Wp bf16, 32x32x16-frag-ready ----
// unit u = (kt16*16 + it2)*64 + lane ; elem e:
//   K = kt16*16 + (lane>>5)*8 + e ; jk = K>>7 ; l = K&127 ; i = it2*32 + (lane&31)
__global__ __launch_bounds__(256) void pack_w(const float* __restrict__ W,
                                              __bf16* __restrict__ Wp) {
    int u = blockIdx.x * 256 + threadIdx.x;
    if (u >= 73728) return;                   // 72 kt16 * 16 it2 * 64
    int lane = u & 63;
    int it2  = (u >> 6) & 15;
    int kt16 = u >> 10;
    int i  = it2 * 32 + (lane & 31);
    int K0 = kt16 * 16 + ((lane >> 5) << 3);
    bvec8 o;
#pragma unroll
    for (int e = 0; e < 8; ++e) {
        int K  = K0 + e;
        int jk = K >> 7;
        int l  = K & 127;
        int j  = (jk * 11) >> 5;              // jk/3 for jk<9
        int k  = jk - 3 * j;
        o[e] = (__bf16)W[((l * 9 + j * 3 + k) << 9) + i];
    }
    *(bvec8*)&Wp[(size_t)u * 8] = o;
}

// per-step body: counted-vmcnt pipeline, 16x mfma 32x32x16
#define STEP(JK, LT, VMN, DO_STAGE)                                            \
  {                                                                            \
    const int cur_ = (LT) & 1;                                                 \
    if ((VMN) == 0) asm volatile("s_waitcnt vmcnt(0)" ::: "memory");           \
    else            asm volatile("s_waitcnt vmcnt(4)" ::: "memory");           \
    __builtin_amdgcn_s_barrier();            /* buf[cur_] fully staged */      \
    asm volatile("" ::: "memory");                                             \
    bvec8 af[2][2], bf[4][2];                                                  \
    _Pragma("unroll")                                                          \
    for (int h = 0; h < 2; ++h) {                                              \
      const int u_ = (LT) * 4 + h * 2 + ls5;                                   \
      _Pragma("unroll")                                                        \
      for (int am = 0; am < 2; ++am) {                                         \
        bvec8 v = *(const bvec8*)&ys[rowE[am] + ((u_ ^ rx[am]) << 3)];         \
        af[am][h] = msk[am] ? v : bzero8();                                    \
      }                                                                        \
      _Pragma("unroll")                                                        \
      for (int ii = 0; ii < 4; ++ii)                                           \
        bf[ii][h] = *(const bvec8*)&wbuf[cur_ * 16384 +                        \
                     ((h * 16 + wi4 + ii) * 64 + lane) * 8];                   \
    }                                                                          \
    asm volatile("s_waitcnt lgkmcnt(0)" ::: "memory");                         \
    __builtin_amdgcn_sched_barrier(0);                                         \
    __builtin_amdgcn_s_barrier();            /* all waves drained buf reads */ \
    asm volatile("" ::: "memory");                                             \
    if (DO_STAGE) stage_tile(WpB, wbufB + cur_ * 32768, (JK) * 4 + (LT) + 2, tid); \
    __builtin_amdgcn_s_setprio(1);                                             \
    _Pragma("unroll")                                                          \
    for (int h = 0; h < 2; ++h)                                                \
      _Pragma("unroll")                                                        \
      for (int am = 0; am < 2; ++am)                                           \
        _Pragma("unroll")                                                      \
        for (int ii = 0; ii < 4; ++ii)                                         \
          acc[am][ii] = __builtin_amdgcn_mfma_f32_32x32x16_bf16(               \
              af[am][h], bf[ii][h], acc[am][ii], 0, 0, 0);                     \
    __builtin_amdgcn_s_setprio(0);                                             \
  }

__device__ __forceinline__ void stage_tile(const char* WpB, char* dst, int tile, int tid) {
    const char* g = WpB + (size_t)tile * 32768 + tid * 16;
    char* d = dst + tid * 16;
#pragma unroll
    for (int r = 0; r < 4; ++r)
        gload16(g + r * 8192, d + r * 8192);
}

// block = 2 batches x 512 i ; 512 thr = 8 waves = (wm 2) x (wi 4)
// ys[bb][row=(n*3+j)*7+w][l 0..127] bf16, 16B-unit swizzle u^=(row&15)
__global__ __launch_bounds__(512, 2) void conv_mfma(
    const float* __restrict__ x, const __bf16* __restrict__ Wp,
    float* __restrict__ out)
{
    extern __shared__ char smem[];
    __bf16* ys   = (__bf16*)smem;               // 2*147*128*2 = 75264 B
    __bf16* wbuf = (__bf16*)(smem + 75264);     // 2 * 32768 B

    const int tid  = threadIdx.x;
    const int wid  = tid >> 6;
    const int lane = tid & 63;
    const int l31  = lane & 31;
    const int ls5  = lane >> 5;
    const int wm   = wid >> 2;                  // batch half
    const int wi   = wid & 3;                   // i-quarter
    const int wi4  = wi * 4;
    const int b0   = blockIdx.x * 2;

    const float* xb = x + (size_t)b0 * (256 * 49);
    const char* WpB = (const char*)Wp;
    char* wbufB = (char*)wbuf;

    // prologue: stage tiles 0,1 (drained by ys-build __syncthreads)
    stage_tile(WpB, wbufB, 0, tid);
    stage_tile(WpB, wbufB + 32768, 1, tid);

    // zero-init A-less rows (0,0,w) and (6,2,w), both batches
    if (tid < 448) {
        int seg  = tid & 15;
        int w    = (tid >> 4) % 7;
        int kind = ((tid >> 4) / 7) & 1;
        int bb   = tid / 224;
        int njw  = kind ? (6 * 3 + 2) * 7 + w : w;
        *(svec8*)&ys[bb * 18816 + njw * 128 + seg * 8] = (svec8)0;
    }
    // phase A: c in [0,128): ys[bb][(r+1-j,j,w)][l] = x
    for (int it = 0; it < 13; ++it) {
        int e = it * 512 + tid;
        if (e < 6272) {
            int w = e % 7, r = (e / 7) % 7, l = e / 49;
#pragma unroll
            for (int bb = 0; bb < 2; ++bb) {
                float v = xb[bb * 12544 + e];
#pragma unroll
                for (int j = 0; j < 3; ++j) {
                    int n = r + 1 - j;
                    if (n >= 0 && n < 7) {
                        int row = (n * 3 + j) * 7 + w;
                        ys[bb * 18816 + row * 128 +
                           (((l >> 3) ^ (row & 15)) << 3) + (l & 7)] = (__bf16)v;
                    }
                }
            }
        }
    }
    __syncthreads();
    // phase B: c in [128,256): ys[bb][((r-j+2)%7,j,w)][l] += x
    for (int it = 0; it < 13; ++it) {
        int e = it * 512 + tid;
        if (e < 6272) {
            int w = e % 7, r = (e / 7) % 7, l = e / 49;
#pragma unroll
            for (int bb = 0; bb < 2; ++bb) {
                float v = xb[bb * 12544 + 6272 + e];
#pragma unroll
                for (int j = 0; j < 3; ++j) {
                    int q = r - j + 1;
                    if (q >= 0 && q < 7) {
                        int n = q + 1; if (n >= 7) n -= 7;
                        int row = (n * 3 + j) * 7 + w;
                        int idx = bb * 18816 + row * 128 +
                                  (((l >> 3) ^ (row & 15)) << 3) + (l & 7);
                        ys[idx] = (__bf16)((float)ys[idx] + v);
                    }
                }
            }
        }
    }

    // row geometry: s = am*32 + l31
    int nn[2], oo[2]; bool sv[2];
#pragma unroll
    for (int am = 0; am < 2; ++am) {
        int s = am * 32 + l31;
        sv[am] = (s < 49);
        int sc = sv[am] ? s : 0;
        nn[am] = sc / 7;
        oo[am] = sc - nn[am] * 7;
    }
    const int ysW = wm * 18816;

    fvec16 acc[2][4];
#pragma unroll
    for (int am = 0; am < 2; ++am)
#pragma unroll
        for (int ii = 0; ii < 4; ++ii)
#pragma unroll
            for (int r = 0; r < 16; ++r) acc[am][ii][r] = 0.f;

    __syncthreads();   // ys complete + tiles 0,1 landed (vmcnt drained)

    int rowE[2], rx[2]; bool msk[2];
    for (int jk = 0; jk < 8; ++jk) {
        int j = (jk * 11) >> 5;
        int k = jk - 3 * j;
#pragma unroll
        for (int am = 0; am < 2; ++am) {
            int tw = oo[am] + k + 5;
            int w = tw >= 7 ? tw - 7 : tw;                  // (o+k+5)%7
            msk[am] = sv[am] && !((k == 0 && oo[am] == 0) || (k == 2 && oo[am] == 6));
            int row = (nn[am] * 3 + j) * 7 + w;
            rowE[am] = ysW + row * 128;
            rx[am]   = row & 15;
        }
        STEP(jk, 0, 4, true)
        STEP(jk, 1, 4, true)
        STEP(jk, 2, 4, true)
        STEP(jk, 3, 4, true)
    }
    {   // jk = 8 peeled (j=2,k=2): stages 34,35 then drain
        const int j = 2, k = 2;
#pragma unroll
        for (int am = 0; am < 2; ++am) {
            int tw = oo[am] + k + 5;
            int w = tw >= 7 ? tw - 7 : tw;
            msk[am] = sv[am] && !(oo[am] == 6);
            int row = (nn[am] * 3 + j) * 7 + w;
            rowE[am] = ysW + row * 128;
            rx[am]   = row & 15;
        }
        STEP(8, 0, 4, true)
        STEP(8, 1, 4, true)
        STEP(8, 2, 4, false)
        STEP(8, 3, 0, false)
    }

    // ---- epilogue: LDS transpose -> coalesced stores ----
    // D: col=l31 -> i_local ; row=(reg&3)+8*(reg>>2)+4*ls5 -> s_local
    float* T = (float*)smem;   // [2][256][36] f32 = 73728 B
#pragma unroll
    for (int p = 0; p < 4; ++p) {
        const int am = p >> 1, ihalf = p & 1;
        __syncthreads();
        if ((wi >> 1) == ihalf) {
            const int irb = (wi & 1) * 128 + l31;
#pragma unroll
            for (int ii = 0; ii < 4; ++ii) {
                int base = (wm * 256 + irb + ii * 32) * 36 + ls5 * 4;
#pragma unroll
                for (int q = 0; q < 4; ++q) {
                    fvec4 v4 = { acc[am][ii][q * 4 + 0], acc[am][ii][q * 4 + 1],
                                 acc[am][ii][q * 4 + 2], acc[am][ii][q * 4 + 3] };
                    *(fvec4*)&T[base + q * 8] = v4;
                }
            }
        }
        __syncthreads();
        if (am == 0) {
#pragma unroll 4
            for (int it = 0; it < 32; ++it) {
                int idx = it * 512 + tid;
                int row = idx >> 5, s = idx & 31;
                int bb = row >> 8, ir = row & 255;
                out[((size_t)(b0 + bb) * 512 + ihalf * 256 + ir) * 49 + s] =
                    T[(bb * 256 + ir) * 36 + s];
            }
        } else {
#pragma unroll 4
            for (int it = 0; it < 17; ++it) {
                int idx = it * 512 + tid;
                int row = idx / 17, s = idx - row * 17;
                int bb = row >> 8, ir = row & 255;
                out[((size_t)(b0 + bb) * 512 + ihalf * 256 + ir) * 49 + 32 + s] =
                    T[(bb * 256 + ir) * 36 + s];
            }
        }
    }
}

extern "C" void kernel_launch(void* const* d_in, const int* in_sizes, int n_in,
                              void* d_out, int out_size, void* d_ws, size_t ws_size,
                              hipStream_t stream) {
    const float* x = (const float*)d_in[0];   // (1024,256,7,7)
    const float* W = (const float*)d_in[1];   // (128,3,3,512)
    float* out = (float*)d_out;               // (1024,512,7,7)
    __bf16* Wp = (__bf16*)d_ws;               // 72*16*64*8 bf16 = 1.18 MB
    (void)in_sizes; (void)n_in; (void)out_size; (void)ws_size;

    static bool attr_set = false;
    if (!attr_set) {
        hipFuncSetAttribute(reinterpret_cast<const void*>(conv_mfma),
                            hipFuncAttributeMaxDynamicSharedMemorySize, 140800);
        attr_set = true;
    }

    hipLaunchKernelGGL(pack_w, dim3(288), dim3(256), 0, stream, W, Wp);
    hipLaunchKernelGGL(conv_mfma, dim3(512), dim3(512), 140800, stream, x, Wp, out);
}

// Round 5
// 120.433 us; speedup vs baseline: 1.2552x; 1.2552x over previous
//
#include <hip/hip_runtime.h>

typedef __attribute__((ext_vector_type(8)))  __bf16 bvec8;
typedef __attribute__((ext_vector_type(16))) float  fvec16;
typedef __attribute__((ext_vector_type(8)))  short  svec8;

// ---- pack W[l][j][k][i] fp32 -> Wp bf16, 32x32x16-frag-ready ----
// unit u = (kt16*16 + it2)*64 + lane ; elem e:
//   K = kt16*16 + (lane>>5)*8 + e ; jk = K>>7 ; l = K&127 ; i = it2*32 + (lane&31)
// K' ordering: K = jk*128 + l, jk = j*3+k
__global__ __launch_bounds__(256) void pack_w(const float* __restrict__ W,
                                              __bf16* __restrict__ Wp) {
    int u = blockIdx.x * 256 + threadIdx.x;
    if (u >= 73728) return;                   // 72 kt16 * 16 it2 * 64
    int lane = u & 63;
    int it2  = (u >> 6) & 15;
    int kt16 = u >> 10;
    int i  = it2 * 32 + (lane & 31);
    int K0 = kt16 * 16 + ((lane >> 5) << 3);
    bvec8 o;
#pragma unroll
    for (int e = 0; e < 8; ++e) {
        int K  = K0 + e;
        int jk = K >> 7;
        int l  = K & 127;
        int j  = (jk * 11) >> 5;              // jk/3 for jk<9
        int k  = jk - 3 * j;
        o[e] = (__bf16)W[((l * 9 + j * 3 + k) << 9) + i];
    }
    *(bvec8*)&Wp[(size_t)u * 8] = o;
}

// ---- main: block = 1 batch x 512 i, 256 thr = 4 waves ----
// MFMA: A = W (row=i), B = activations (col=s), D[i][s] -> direct coalesced stores.
// ys[row=(n*3+j)*7+w][l 0..127] bf16, 16B-unit swizzle u^=(row&15); row 147 = zeros.
__global__ __launch_bounds__(256, 2) void conv_mfma(
    const float* __restrict__ x, const __bf16* __restrict__ Wp,
    float* __restrict__ out)
{
    __shared__ __bf16 ys[148 * 128];          // 37888 B

    const int tid  = threadIdx.x;
    const int lane = tid & 63;
    const int l31  = lane & 31;
    const int ls5  = lane >> 5;
    const int wv   = tid >> 6;                // wave 0..3 -> i-tiles wv*4..wv*4+3
    const int b    = blockIdx.x;

    const float* xb = x + (size_t)b * 12544;
    const char*  WpB = (const char*)Wp;

    // ---- W double buffers in registers; prologue: tiles 0,1 in flight during build
    bvec8 aE[4][2], aO[4][2];
    {
        const char* g = WpB + ((size_t)lane << 4);
#pragma unroll
        for (int am = 0; am < 4; ++am)
#pragma unroll
            for (int h = 0; h < 2; ++h) {
                aE[am][h] = *(const bvec8*)(g + ((h * 16 + wv * 4 + am) << 10));
                aO[am][h] = *(const bvec8*)(g + 32768 + ((h * 16 + wv * 4 + am) << 10));
            }
    }

    // ---- zero rows with no phase-A contribution + the zero-row 147
    // rows 0..6 (n=0,j=0), 140..146 (n=6,j=2), 147
    if (tid < 240) {
        int rowz = tid >> 4;
        int row  = rowz < 7 ? rowz : (rowz < 14 ? 133 + rowz : 147);
        *(svec8*)&ys[(row << 7) + ((tid & 15) << 3)] = (svec8)0;
    }

    // ---- phase A: c in [0,128): ys[(r+1-j,j,w)][l] = x[b,l,r,w]
    for (int it = 0; it < 25; ++it) {
        int e = it * 256 + tid;
        if (e < 6272) {
            int w = e % 7, r = (e / 7) % 7, l = e / 49;
            float v = xb[e];
#pragma unroll
            for (int j = 0; j < 3; ++j) {
                int n = r + 1 - j;
                if (n >= 0 && n < 7) {
                    int row = (n * 3 + j) * 7 + w;
                    ys[(row << 7) + (((l >> 3) ^ (row & 15)) << 3) + (l & 7)] = (__bf16)v;
                }
            }
        }
    }
    __syncthreads();
    // ---- phase B: c in [128,256): ys[((r-j+2)%7,j,w)][l] += x[b,128+l,r,w]
    for (int it = 0; it < 25; ++it) {
        int e = it * 256 + tid;
        if (e < 6272) {
            int w = e % 7, r = (e / 7) % 7, l = e / 49;
            float v = xb[6272 + e];
#pragma unroll
            for (int j = 0; j < 3; ++j) {
                int q = r - j + 1;
                if (q >= 0 && q < 7) {
                    int n = q + 1; if (n >= 7) n -= 7;
                    int row = (n * 3 + j) * 7 + w;
                    int idx = (row << 7) + (((l >> 3) ^ (row & 15)) << 3) + (l & 7);
                    ys[idx] = (__bf16)((float)ys[idx] + v);
                }
            }
        }
    }

    // ---- per-lane column geometry: s = sn*32 + l31
    int nn[2], oo[2];
#pragma unroll
    for (int sn = 0; sn < 2; ++sn) {
        int s = sn * 32 + l31;
        int sc = (s < 49) ? s : 0;
        nn[sn] = sc / 7;
        oo[sn] = sc - nn[sn] * 7;
    }

    fvec16 acc[4][2];
#pragma unroll
    for (int am = 0; am < 4; ++am)
#pragma unroll
        for (int sn = 0; sn < 2; ++sn)
#pragma unroll
            for (int r = 0; r < 16; ++r) acc[am][sn][r] = 0.f;

    __syncthreads();   // ys complete; no further barriers

    // ---- K-loop: 9 jk-groups x 4 K32-tiles, zero barriers, reg-dbuf W
    for (int jk = 0; jk < 9; ++jk) {
        const int j = (jk * 11) >> 5;
        const int k = jk - 3 * j;
        int rowB[2], rx[2];
#pragma unroll
        for (int sn = 0; sn < 2; ++sn) {
            int o  = oo[sn];
            int tw = o + k + 5;
            int w  = tw >= 7 ? tw - 7 : tw;                    // (o+k+5)%7
            int row = (nn[sn] * 3 + j) * 7 + w;
            if ((k == 0 && o == 0) || (k == 2 && o == 6)) row = 147;  // zero row
            rowB[sn] = row << 7;
            rx[sn]   = row & 15;
        }
#pragma unroll
        for (int p = 0; p < 4; ++p) {
            const int t = jk * 4 + p;
            // activation fragments for this tile (B operand)
            bvec8 bf[2][2];
#pragma unroll
            for (int sn = 0; sn < 2; ++sn)
#pragma unroll
                for (int h = 0; h < 2; ++h) {
                    int u = (p * 4 + h * 2 + ls5) ^ rx[sn];
                    bf[sn][h] = *(const bvec8*)&ys[rowB[sn] + (u << 3)];
                }
            __builtin_amdgcn_s_setprio(1);
            if ((p & 1) == 0) {
#pragma unroll
                for (int h = 0; h < 2; ++h)
#pragma unroll
                    for (int am = 0; am < 4; ++am)
#pragma unroll
                        for (int sn = 0; sn < 2; ++sn)
                            acc[am][sn] = __builtin_amdgcn_mfma_f32_32x32x16_bf16(
                                aE[am][h], bf[sn][h], acc[am][sn], 0, 0, 0);
            } else {
#pragma unroll
                for (int h = 0; h < 2; ++h)
#pragma unroll
                    for (int am = 0; am < 4; ++am)
#pragma unroll
                        for (int sn = 0; sn < 2; ++sn)
                            acc[am][sn] = __builtin_amdgcn_mfma_f32_32x32x16_bf16(
                                aO[am][h], bf[sn][h], acc[am][sn], 0, 0, 0);
            }
            __builtin_amdgcn_s_setprio(0);
            // prefetch tile t+2 into the buffer just consumed
            if (t + 2 < 36) {
                const char* g = WpB + ((size_t)(t + 2) << 15) + ((size_t)lane << 4);
                if ((p & 1) == 0) {
#pragma unroll
                    for (int am = 0; am < 4; ++am)
#pragma unroll
                        for (int h = 0; h < 2; ++h)
                            aE[am][h] = *(const bvec8*)(g + ((h * 16 + wv * 4 + am) << 10));
                } else {
#pragma unroll
                    for (int am = 0; am < 4; ++am)
#pragma unroll
                        for (int h = 0; h < 2; ++h)
                            aO[am][h] = *(const bvec8*)(g + ((h * 16 + wv * 4 + am) << 10));
                }
            }
        }
    }

    // ---- epilogue: direct stores. D: row=(r&3)+8*(r>>2)+4*ls5 -> i ; col=l31 -> s
    const size_t obase = (size_t)b * 25088;    // 512*49
#pragma unroll
    for (int am = 0; am < 4; ++am) {
        const int i0 = (wv * 4 + am) * 32 + 4 * ls5;
#pragma unroll
        for (int sn = 0; sn < 2; ++sn) {
            const int s = sn * 32 + l31;
            if (sn == 1 && l31 >= 17) continue;   // invalid cols (s>=49)
#pragma unroll
            for (int r = 0; r < 16; ++r) {
                int i = i0 + (r & 3) + 8 * (r >> 2);
                out[obase + (size_t)i * 49 + s] = acc[am][sn][r];
            }
        }
    }
}

extern "C" void kernel_launch(void* const* d_in, const int* in_sizes, int n_in,
                              void* d_out, int out_size, void* d_ws, size_t ws_size,
                              hipStream_t stream) {
    const float* x = (const float*)d_in[0];   // (1024,256,7,7)
    const float* W = (const float*)d_in[1];   // (128,3,3,512)
    float* out = (float*)d_out;               // (1024,512,7,7)
    __bf16* Wp = (__bf16*)d_ws;               // 72*16*64*8 bf16 = 1.18 MB
    (void)in_sizes; (void)n_in; (void)out_size; (void)ws_size;

    hipLaunchKernelGGL(pack_w, dim3(288), dim3(256), 0, stream, W, Wp);
    hipLaunchKernelGGL(conv_mfma, dim3(1024), dim3(256), 0, stream, x, Wp, out);
}

// Round 6
// 101.314 us; speedup vs baseline: 1.4921x; 1.1887x over previous
//
#include <hip/hip_runtime.h>

typedef __attribute__((ext_vector_type(8)))  __bf16 bvec8;
typedef __attribute__((ext_vector_type(4)))  __bf16 bvec4;
typedef __attribute__((ext_vector_type(16))) float  fvec16;
typedef __attribute__((ext_vector_type(8)))  short  svec8;

// ---- pack W[l][j][k][i] fp32 -> Wp bf16, 32x32x16-frag-ready ----
// unit u = (kt16*16 + it2)*64 + lane ; elem e:
//   K = kt16*16 + (lane>>5)*8 + e ; jk = K>>7 ; l = K&127 ; i = it2*32 + (lane&31)
__global__ __launch_bounds__(256) void pack_w(const float* __restrict__ W,
                                              __bf16* __restrict__ Wp) {
    int u = blockIdx.x * 256 + threadIdx.x;
    if (u >= 73728) return;                   // 72 kt16 * 16 it2 * 64
    int lane = u & 63;
    int it2  = (u >> 6) & 15;
    int kt16 = u >> 10;
    int i  = it2 * 32 + (lane & 31);
    int K0 = kt16 * 16 + ((lane >> 5) << 3);
    bvec8 o;
#pragma unroll
    for (int e = 0; e < 8; ++e) {
        int K  = K0 + e;
        int jk = K >> 7;
        int l  = K & 127;
        int j  = (jk * 11) >> 5;              // jk/3 for jk<9
        int k  = jk - 3 * j;
        o[e] = (__bf16)W[((l * 9 + j * 3 + k) << 9) + i];
    }
    *(bvec8*)&Wp[(size_t)u * 8] = o;
}

// ---- main: block = 1 batch x 512 i, 512 thr = 8 waves ----
// wave wv: i-tiles {2wv, 2wv+1} (am=2), both s-tiles (sn=2).
// MFMA: A = W (row=i), B = activations (col=s); D[i][s] -> direct stores.
// ys[row=(n*3+j)*7+w][l 0..127], 16B-unit swizzle u^=(row&15); row 147 = zeros.
__global__ __launch_bounds__(512, 4) void conv_mfma(
    const float* __restrict__ x, const __bf16* __restrict__ Wp,
    float* __restrict__ out)
{
    __shared__ __bf16 xs[12544];              // [l 0..255][c=r*7+w] 25088 B
    __shared__ __bf16 ys[148 * 128];          // 37888 B

    const int tid  = threadIdx.x;
    const int lane = tid & 63;
    const int l31  = lane & 31;
    const int ls5  = lane >> 5;
    const int wv   = tid >> 6;                // wave 0..7
    const int b    = blockIdx.x;

    const float* xb = x + (size_t)b * 12544;
    const char*  WpB = (const char*)Wp;

    // ---- W reg-dbuf prologue: tiles 0,1 in flight during build ----
    // unit(am,h) = h*16 + wv*2 + am ; offset = unit*1024 + lane*16
    bvec8 aE[2][2], aO[2][2];
    {
        const char* g = WpB + ((size_t)lane << 4);
#pragma unroll
        for (int am = 0; am < 2; ++am)
#pragma unroll
            for (int h = 0; h < 2; ++h) {
                const int unit = h * 16 + wv * 2 + am;
                aE[am][h] = *(const bvec8*)(g + (unit << 10));
                aO[am][h] = *(const bvec8*)(g + 32768 + (unit << 10));
            }
    }

    // ---- pass 1: x (f32) -> xs (bf16), float4-vectorized, coalesced ----
    for (int it = 0; it < 7; ++it) {
        int e4 = it * 512 + tid;
        if (e4 < 3136) {
            const float4 v = ((const float4*)xb)[e4];
            bvec4 pk = { (__bf16)v.x, (__bf16)v.y, (__bf16)v.z, (__bf16)v.w };
            *(bvec4*)&xs[e4 * 4] = pk;
        }
    }
    __syncthreads();

    // ---- pass 2: write-once ys build (no RMW, no zero-init pass) ----
    // unit u' = row*16 + useg ; l = useg*8 + d
    // maskA: rA = n+j-1 in [0,7) ; maskB: !(j==0&&n==1) && !(j==2&&n==0), rB=(n+j+5)%7
    for (int it = 0; it < 5; ++it) {
        int up = it * 512 + tid;
        if (up < 2368) {
            int row  = up >> 4;
            int useg = up & 15;
            bvec8 ov;
            if (row >= 147) {
                ov = __builtin_bit_cast(bvec8, (svec8)0);
                row = 147;
            } else {
                int w   = row % 7;
                int njq = row / 7;
                int j   = njq % 3;
                int n   = njq / 3;
                int rA  = n + j - 1;
                bool mA = (unsigned)rA < 7u;
                int rB  = n + j + 5; if (rB >= 7) rB -= 7; if (rB >= 7) rB -= 7;
                bool mB = !((j == 0 && n == 1) || (j == 2 && n == 0));
                int cA  = rA * 7 + w;
                int cB  = rB * 7 + w;
                int l0  = useg * 8;
#pragma unroll
                for (int d = 0; d < 8; ++d) {
                    float fa = mA ? (float)xs[(l0 + d) * 49 + cA] : 0.f;
                    float fb = mB ? (float)xs[(128 + l0 + d) * 49 + cB] : 0.f;
                    ov[d] = (__bf16)(fa + fb);
                }
            }
            *(bvec8*)&ys[(row << 7) + ((useg ^ (row & 15)) << 3)] = ov;
        }
    }

    // ---- per-lane column geometry: s = sn*32 + l31 ----
    int nn21[2], oo[2];
#pragma unroll
    for (int sn = 0; sn < 2; ++sn) {
        int s = sn * 32 + l31;
        int sc = (s < 49) ? s : 48;
        int n = sc / 7;
        nn21[sn] = n * 21;
        oo[sn]   = sc - n * 7;
    }

    fvec16 acc[2][2];
#pragma unroll
    for (int am = 0; am < 2; ++am)
#pragma unroll
        for (int sn = 0; sn < 2; ++sn)
#pragma unroll
            for (int r = 0; r < 16; ++r) acc[am][sn][r] = 0.f;

    __syncthreads();   // ys complete; no further barriers

    // ---- K-loop: 9 jk-groups x 4 tiles, zero barriers, reg-dbuf W ----
    for (int jk = 0; jk < 9; ++jk) {
        const int j = (jk * 11) >> 5;
        const int k = jk - 3 * j;
        int rowB[2], rx[2];
#pragma unroll
        for (int sn = 0; sn < 2; ++sn) {
            int o  = oo[sn];
            int tw = o + k + 5;
            int w  = tw >= 7 ? tw - 7 : tw;                 // (o+k+5)%7
            int row = nn21[sn] + j * 7 + w;
            if ((k == 0 && o == 0) || (k == 2 && o == 6)) row = 147;  // zero row
            rowB[sn] = row << 7;
            rx[sn]   = row & 15;
        }
#pragma unroll
        for (int p = 0; p < 4; ++p) {
            const int t = jk * 4 + p;
            bvec8 bf[2][2];
#pragma unroll
            for (int sn = 0; sn < 2; ++sn)
#pragma unroll
                for (int h = 0; h < 2; ++h) {
                    int u = (p * 4 + h * 2 + ls5) ^ rx[sn];
                    bf[sn][h] = *(const bvec8*)&ys[rowB[sn] + (u << 3)];
                }
            __builtin_amdgcn_s_setprio(1);
            if ((p & 1) == 0) {
#pragma unroll
                for (int h = 0; h < 2; ++h)
#pragma unroll
                    for (int am = 0; am < 2; ++am)
#pragma unroll
                        for (int sn = 0; sn < 2; ++sn)
                            acc[am][sn] = __builtin_amdgcn_mfma_f32_32x32x16_bf16(
                                aE[am][h], bf[sn][h], acc[am][sn], 0, 0, 0);
            } else {
#pragma unroll
                for (int h = 0; h < 2; ++h)
#pragma unroll
                    for (int am = 0; am < 2; ++am)
#pragma unroll
                        for (int sn = 0; sn < 2; ++sn)
                            acc[am][sn] = __builtin_amdgcn_mfma_f32_32x32x16_bf16(
                                aO[am][h], bf[sn][h], acc[am][sn], 0, 0, 0);
            }
            __builtin_amdgcn_s_setprio(0);
            // prefetch tile t+2 into the buffer just consumed
            if (t + 2 < 36) {
                const char* g = WpB + ((size_t)(t + 2) << 15) + ((size_t)lane << 4);
                if ((p & 1) == 0) {
#pragma unroll
                    for (int am = 0; am < 2; ++am)
#pragma unroll
                        for (int h = 0; h < 2; ++h)
                            aE[am][h] = *(const bvec8*)(g + ((h * 16 + wv * 2 + am) << 10));
                } else {
#pragma unroll
                    for (int am = 0; am < 2; ++am)
#pragma unroll
                        for (int h = 0; h < 2; ++h)
                            aO[am][h] = *(const bvec8*)(g + ((h * 16 + wv * 2 + am) << 10));
                }
            }
        }
    }

    // ---- epilogue: D row=(r&3)+8*(r>>2)+4*ls5 -> i ; col=l31 -> s ----
    const size_t obase = (size_t)b * 25088;   // 512*49
#pragma unroll
    for (int am = 0; am < 2; ++am) {
        const int i0 = (wv * 2 + am) * 32 + 4 * ls5;
#pragma unroll
        for (int sn = 0; sn < 2; ++sn) {
            const int s = sn * 32 + l31;
            if (sn == 1 && l31 >= 17) continue;   // s >= 49
#pragma unroll
            for (int r = 0; r < 16; ++r) {
                int i = i0 + (r & 3) + 8 * (r >> 2);
                out[obase + (size_t)i * 49 + s] = acc[am][sn][r];
            }
        }
    }
}

extern "C" void kernel_launch(void* const* d_in, const int* in_sizes, int n_in,
                              void* d_out, int out_size, void* d_ws, size_t ws_size,
                              hipStream_t stream) {
    const float* x = (const float*)d_in[0];   // (1024,256,7,7)
    const float* W = (const float*)d_in[1];   // (128,3,3,512)
    float* out = (float*)d_out;               // (1024,512,7,7)
    __bf16* Wp = (__bf16*)d_ws;               // 72*16*64*8 bf16 = 1.18 MB
    (void)in_sizes; (void)n_in; (void)out_size; (void)ws_size;

    hipLaunchKernelGGL(pack_w, dim3(288), dim3(256), 0, stream, W, Wp);
    hipLaunchKernelGGL(conv_mfma, dim3(1024), dim3(512), 0, stream, x, Wp, out);
}